// Round 21
// baseline (12076.324 us; speedup 1.0000x reference)
//
#include <hip/hip_runtime.h>

#define BB 256
#define TT 100
#define HH 512
#define G4 2048
#define INL 176
#define KIN 192
#define NCAT 16
#define NCONT 48
#define VV 32
#define EE 8
#define MTOT (BB*TT)
#define HP 520   // LDS h pitch (u16): chunk multiplier 65 (odd) -> conflict-free b128

typedef unsigned short u16;
typedef unsigned int   u32;
typedef __attribute__((ext_vector_type(8))) short bf16x8;
typedef __attribute__((ext_vector_type(4))) float f32x4;

__device__ __forceinline__ float bf2f(u16 u){
    union { u32 i; float f; } v; v.i = ((u32)u) << 16; return v.f;
}
__device__ __forceinline__ u16 f2bf(float f){
    union { float f; u32 i; } v; v.f = f;
    u32 b = v.i;
    b += 0x7FFFu + ((b >> 16) & 1u);   // round-to-nearest-even
    return (u16)(b >> 16);
}

// ---- canonical-name kernel: W_in fp32 [176][512] -> bf16 WinT [512][192] (pad) ----
__global__ void PredictionModel_58841051955204_kernel(
    const float* __restrict__ Win, u16* __restrict__ WinT){
    int idx = blockIdx.x*256 + threadIdx.x;
    if (idx >= HH*KIN) return;
    int h = idx / KIN, i = idx % KIN;
    WinT[idx] = (i < INL) ? f2bf(Win[i*HH + h]) : (u16)0;
}

// ---- bulk fp32 -> bf16 convert (weights) ----
__global__ void k_cvt(const float* __restrict__ in, u16* __restrict__ out, int n){
    int i = blockIdx.x*256 + threadIdx.x;
    if (i < n) out[i] = f2bf(in[i]);
}

// ---- featurize: fp32 inputs -> bf16 feat [25600][192] ----
__global__ void k_feat(const float* __restrict__ x, const float* __restrict__ mean,
                       const float* __restrict__ scale, const float* __restrict__ emb,
                       u16* __restrict__ feat){
    int idx = blockIdx.x*256 + threadIdx.x;
    int bt = idx >> 4, g = idx & 15;
    if (bt >= MTOT) return;
    const float* xr = x + (size_t)bt*64;
    u16* fr = feat + (size_t)bt*KIN;
    int k0 = g*4;
    int ci = (int)xr[k0];
    if (ci < 0) ci = 0;
    if (ci > VV-1) ci = VV-1;
    const float* ep = emb + (size_t)(g*VV + ci)*EE;
    int c0 = g*11;
    for (int e = 0; e < 8; e++) fr[c0+e] = f2bf(ep[e]);
    for (int j = 1; j <= 3; j++){
        int k = k0 + j;
        fr[c0 + 8 + (j-1)] = f2bf((xr[k] - mean[k]) / scale[k]);
    }
    fr[INL + g] = 0;
}

// ---- MFMA GEMM: out[m,n] = act(A(bf16) @ W(bf16 [N][K])^T + b1 + b2) ----
__global__ __launch_bounds__(256) void k_gemm(
    const u16* __restrict__ A, int lda,
    const u16* __restrict__ W, int K,
    const float* __restrict__ bias1, const float* __restrict__ bias2,
    void* __restrict__ out, int ldo, int kc_cnt, int do_relu, int out_half)
{
    __shared__ u16 sA[64*40];
    __shared__ u16 sB[256*40];
    int tid = threadIdx.x;
    int w = tid >> 6, lane = tid & 63, q = lane >> 4, r = lane & 15;
    int m0 = blockIdx.x * 64;
    int n0 = blockIdx.y * 256;

    f32x4 acc[4][4];
    for (int a_ = 0; a_ < 4; a_++)
        for (int b_ = 0; b_ < 4; b_++){
            acc[a_][b_][0] = 0.f; acc[a_][b_][1] = 0.f;
            acc[a_][b_][2] = 0.f; acc[a_][b_][3] = 0.f;
        }

    for (int kc = 0; kc < kc_cnt; kc++){
        {
            int row = tid >> 2, seg = tid & 3;
            uint4 v = *(const uint4*)(A + (size_t)(m0+row)*lda + kc*32 + seg*8);
            *(uint4*)(&sA[row*40 + seg*8]) = v;
            const u16* wr = W + (size_t)(n0 + tid)*K + kc*32;
            uint4 b0 = *(const uint4*)(wr);
            uint4 b1 = *(const uint4*)(wr+8);
            uint4 b2 = *(const uint4*)(wr+16);
            uint4 b3 = *(const uint4*)(wr+24);
            u16* d = &sB[tid*40];
            *(uint4*)(d)    = b0; *(uint4*)(d+8)  = b1;
            *(uint4*)(d+16) = b2; *(uint4*)(d+24) = b3;
        }
        __syncthreads();
        bf16x8 a[4], b[4];
        for (int mt = 0; mt < 4; mt++) a[mt] = *(const bf16x8*)(&sA[(mt*16 + r)*40 + q*8]);
        for (int i = 0; i < 4; i++)    b[i]  = *(const bf16x8*)(&sB[((w*4+i)*16 + r)*40 + q*8]);
        for (int mt = 0; mt < 4; mt++)
            for (int i = 0; i < 4; i++)
                acc[mt][i] = __builtin_amdgcn_mfma_f32_16x16x32_bf16(a[mt], b[i], acc[mt][i], 0, 0, 0);
        __syncthreads();
    }

    for (int i = 0; i < 4; i++){
        int n = n0 + (w*4+i)*16 + r;
        float bs = 0.f;
        if (bias1) bs += bias1[n];
        if (bias2) bs += bias2[n];
        for (int mt = 0; mt < 4; mt++){
            for (int reg = 0; reg < 4; reg++){
                int m = m0 + mt*16 + q*4 + reg;
                float v = acc[mt][i][reg] + bs;
                if (do_relu) v = fmaxf(v, 0.f);
                if (out_half) ((_Float16*)out)[(size_t)m*ldo + n] = (_Float16)v;
                else          ((u16*)out)[(size_t)m*ldo + n] = f2bf(v);
            }
        }
    }
}

// ---- BARRIER-FREE persistent recurrence: 16 blocks x 16 batch rows ----
// Block owns rows [bid*16, bid*16+16): computes ALL 2048 gates for them, so h/c
// never leave the block. h double-buffered in LDS (2 x 16x520 u16), c in regs.
// 1024 threads = 16 waves; wave w owns jb in {2w, 2w+1} x 4 gates (8 MFMA tiles).
// Gates of cell (m,j) land in one lane (C-layout: col=r=j-offset, row=q*4+reg=m).
// Whh streams from L2 (t-invariant row pointers); xw/Xout are non-temporal so the
// 105 MB stream does not evict Whh from L2.
__global__ __launch_bounds__(1024) void k_rec_seq(
    const u16* __restrict__ Whhb,       // bf16 [2048][512] layer slice
    const _Float16* __restrict__ xw,    // [MTOT][2048], biases folded
    u16* __restrict__ hFin,             // bf16 [256][512]: final h out (t=TT-1)
    u16* __restrict__ Xout)             // relu(h) sequence (layer 0) or null
{
    __shared__ __align__(16) u16 sH[2][16*HP];
    int tid = threadIdx.x;
    int w = tid >> 6, lane = tid & 63, q = lane >> 4, r = lane & 15;
    int m0 = blockIdx.x * 16;

    // zero h buffer 0 (t=0 reads zeros)
    for (int i = tid; i < 16*HP; i += 1024) sH[0][i] = 0;

    // t-invariant B row pointers: tile (i=jb-half, g): rows n = g*512 + (2w+i)*16 + r
    const u16* bptr[2][4];
    for (int i = 0; i < 2; i++)
        for (int g = 0; g < 4; g++)
            bptr[i][g] = Whhb + (size_t)(g*HH + (w*2+i)*16 + r)*HH + q*8;

    // t-invariant xw bases: cell (i, reg): row bt = (m0+q*4+reg)*TT + t, col j = (2w+i)*16+r
    const _Float16* xb[2][4];
    for (int i = 0; i < 2; i++)
        for (int reg = 0; reg < 4; reg++)
            xb[i][reg] = xw + (size_t)(m0 + q*4 + reg)*TT*G4 + (w*2+i)*16 + r;

    float creg[2][4];
    for (int i = 0; i < 2; i++)
        for (int reg = 0; reg < 4; reg++) creg[i][reg] = 0.f;

    const int aoff = r*HP + q*8;   // A-frag LDS offset (row m=r, k-chunk q)
    __syncthreads();

    for (int t = 0; t < TT; t++){
        const u16* hsrc = &sH[t & 1][0];
        u16*       hdst = &sH[(t + 1) & 1][0];

        f32x4 acc[2][4];
        for (int i = 0; i < 2; i++)
            for (int g = 0; g < 4; g++){
                acc[i][g][0] = 0.f; acc[i][g][1] = 0.f;
                acc[i][g][2] = 0.f; acc[i][g][3] = 0.f;
            }

        for (int kc = 0; kc < 16; kc++){
            bf16x8 a = *(const bf16x8*)(hsrc + aoff + kc*32);
            for (int i = 0; i < 2; i++)
                for (int g = 0; g < 4; g++){
                    bf16x8 b = *(const bf16x8*)(bptr[i][g] + kc*32);
                    acc[i][g] = __builtin_amdgcn_mfma_f32_16x16x32_bf16(a, b, acc[i][g], 0, 0, 0);
                }
        }

        // cell update: 8 cells/lane (2 jb x 4 m), all 4 gates in-lane
        for (int i = 0; i < 2; i++){
            int j = (w*2+i)*16 + r;
            for (int reg = 0; reg < 4; reg++){
                const _Float16* xr = xb[i][reg] + (size_t)t*G4;
                float Gi = acc[i][0][reg] + (float)__builtin_nontemporal_load(xr + 0*HH);
                float Gf = acc[i][1][reg] + (float)__builtin_nontemporal_load(xr + 1*HH);
                float Gg = acc[i][2][reg] + (float)__builtin_nontemporal_load(xr + 2*HH);
                float Go = acc[i][3][reg] + (float)__builtin_nontemporal_load(xr + 3*HH);
                float iv = 1.f/(1.f + __expf(-Gi));
                float fv = 1.f/(1.f + __expf(-Gf));
                float gv = tanhf(Gg);
                float ov = 1.f/(1.f + __expf(-Go));
                float c = fv * creg[i][reg] + iv * gv;
                creg[i][reg] = c;
                float h = ov * tanhf(c);
                u16 h16 = f2bf(h);
                int m = q*4 + reg;
                hdst[m*HP + j] = h16;
                if (Xout){
                    size_t bt = (size_t)(m0 + m)*TT + t;
                    __builtin_nontemporal_store(f2bf(fmaxf(h, 0.f)), Xout + bt*HH + j);
                }
                if (t == TT-1) hFin[(m0 + m)*HH + j] = h16;
            }
        }
        __syncthreads();   // hdst visible before next step's A reads
    }
}

// ---- heads: fp32 output (d_out is float*), zero-sentinel kept ----
__global__ void k_heads(
    const u16* __restrict__ hfin, const float* __restrict__ Wout,
    const float* __restrict__ bout, const float* __restrict__ Wcls,
    const float* __restrict__ bcls, float* __restrict__ out)
{
    __shared__ float last[HH];
    int b = blockIdx.x, tid = threadIdx.x;
    for (int h = tid; h < HH; h += 256) last[h] = fmaxf(bf2f(hfin[b*HH + h]), 0.f);
    __syncthreads();
    for (int o = tid; o < NCONT + NCAT*VV; o += 256){
        if (o < NCONT){
            float a = bout[o];
            for (int h = 0; h < HH; h++) a += last[h] * Wout[h*NCONT + o];
            out[b*NCONT + o] = (a == 0.0f) ? 7.0f : a;
        } else {
            int oc = o - NCONT;
            int n = oc >> 5, v = oc & 31;
            float a = bcls[oc];
            const float* wp = Wcls + (size_t)n*HH*VV + v;
            for (int h = 0; h < HH; h++) a += last[h] * wp[h*VV];
            out[BB*NCONT + b*(NCAT*VV) + oc] = (a == 0.0f) ? 7.0f : a;
        }
    }
}

extern "C" void kernel_launch(void* const* d_in, const int* in_sizes, int n_in,
                              void* d_out, int out_size, void* d_ws, size_t ws_size,
                              hipStream_t stream){
    const float* x      = (const float*)d_in[0];
    const float* smean  = (const float*)d_in[1];
    const float* sscale = (const float*)d_in[2];
    const float* emb    = (const float*)d_in[3];
    const float* Win    = (const float*)d_in[4];
    const float* bin    = (const float*)d_in[5];
    const float* Wih    = (const float*)d_in[6];
    const float* Whh    = (const float*)d_in[7];
    const float* bih    = (const float*)d_in[8];
    const float* bhh    = (const float*)d_in[9];
    const float* Wout   = (const float*)d_in[10];
    const float* bout   = (const float*)d_in[11];
    const float* Wcls   = (const float*)d_in[12];
    const float* bcls   = (const float*)d_in[13];
    (void)in_sizes; (void)n_in; (void)out_size;

    char* ws = (char*)d_ws;
    size_t off = 0;
    u16*      feat  = (u16*)(ws + off);      off += (size_t)MTOT*KIN*2;   //   9.8 MB
    u16*      WinTb = (u16*)(ws + off);      off += (size_t)HH*KIN*2;     //   0.2 MB
    u16*      Xbuf  = (u16*)(ws + off);      off += (size_t)MTOT*HH*2;    //  26.2 MB
    _Float16* xw    = (_Float16*)(ws + off); off += (size_t)MTOT*G4*2;    // 104.9 MB
    u16*      Wihb  = (u16*)(ws + off);      off += (size_t)2*G4*HH*2;    //   4.2 MB
    u16*      Whhb  = (u16*)(ws + off);      off += (size_t)2*G4*HH*2;    //   4.2 MB
    u16*      hFin  = (u16*)(ws + off);      off += (size_t)BB*HH*2;
    (void)off; (void)ws_size;

    // weight prep (bf16 once)
    PredictionModel_58841051955204_kernel<<<384, 256, 0, stream>>>(Win, WinTb);
    k_cvt<<<8192, 256, 0, stream>>>(Wih, Wihb, 2*G4*HH);
    k_cvt<<<8192, 256, 0, stream>>>(Whh, Whhb, 2*G4*HH);

    k_feat<<<1600, 256, 0, stream>>>(x, smean, sscale, emb, feat);
    // h0 = relu(feat @ W_in + b_in) -> Xbuf (bf16)
    k_gemm<<<dim3(400, 2), 256, 0, stream>>>(feat, KIN, WinTb, KIN, bin, (const float*)0,
                                             Xbuf, HH, 6, 1, 0);
    for (int l = 0; l < 2; l++){
        // xw = Xbuf @ Wih_l^T + bih_l + bhh_l -> fp16 (Xbuf consumed before rec overwrites it)
        k_gemm<<<dim3(400, 8), 256, 0, stream>>>(Xbuf, HH, Wihb + (size_t)l*G4*HH, HH,
                                                 bih + l*G4, bhh + l*G4,
                                                 xw, G4, 16, 0, 1);
        k_rec_seq<<<16, 1024, 0, stream>>>(Whhb + (size_t)l*G4*HH, xw, hFin,
                                           (l == 0) ? Xbuf : (u16*)0);
    }
    // heads read final h (written at t=TT-1); fp32 d_out
    k_heads<<<256, 256, 0, stream>>>(hFin, Wout, bout, Wcls, bcls, (float*)d_out);
}

// Round 22
// 2369.757 us; speedup vs baseline: 5.0960x; 5.0960x over previous
//
#include <hip/hip_runtime.h>

#define BB 256
#define TT 100
#define HH 512
#define G4 2048
#define INL 176
#define KIN 192
#define NCAT 16
#define NCONT 48
#define VV 32
#define EE 8
#define MTOT (BB*TT)
#define GRPB 32   // j-blocks per m-group

typedef unsigned short u16;
typedef unsigned int   u32;
typedef __attribute__((ext_vector_type(8))) short bf16x8;
typedef __attribute__((ext_vector_type(4))) float f32x4;

__device__ __forceinline__ float bf2f(u16 u){
    union { u32 i; float f; } v; v.i = ((u32)u) << 16; return v.f;
}
__device__ __forceinline__ u16 f2bf(float f){
    union { float f; u32 i; } v; v.f = f;
    u32 b = v.i;
    b += 0x7FFFu + ((b >> 16) & 1u);   // round-to-nearest-even
    return (u16)(b >> 16);
}

// ---- canonical-name kernel: W_in fp32 [176][512] -> bf16 WinT [512][192] (pad) ----
__global__ void PredictionModel_58841051955204_kernel(
    const float* __restrict__ Win, u16* __restrict__ WinT){
    int idx = blockIdx.x*256 + threadIdx.x;
    if (idx >= HH*KIN) return;
    int h = idx / KIN, i = idx % KIN;
    WinT[idx] = (i < INL) ? f2bf(Win[i*HH + h]) : (u16)0;
}

// ---- bulk fp32 -> bf16 convert (weights) ----
__global__ void k_cvt(const float* __restrict__ in, u16* __restrict__ out, int n){
    int i = blockIdx.x*256 + threadIdx.x;
    if (i < n) out[i] = f2bf(in[i]);
}

// ---- featurize: fp32 inputs -> bf16 feat [25600][192] ----
__global__ void k_feat(const float* __restrict__ x, const float* __restrict__ mean,
                       const float* __restrict__ scale, const float* __restrict__ emb,
                       u16* __restrict__ feat){
    int idx = blockIdx.x*256 + threadIdx.x;
    int bt = idx >> 4, g = idx & 15;
    if (bt >= MTOT) return;
    const float* xr = x + (size_t)bt*64;
    u16* fr = feat + (size_t)bt*KIN;
    int k0 = g*4;
    int ci = (int)xr[k0];
    if (ci < 0) ci = 0;
    if (ci > VV-1) ci = VV-1;
    const float* ep = emb + (size_t)(g*VV + ci)*EE;
    int c0 = g*11;
    for (int e = 0; e < 8; e++) fr[c0+e] = f2bf(ep[e]);
    for (int j = 1; j <= 3; j++){
        int k = k0 + j;
        fr[c0 + 8 + (j-1)] = f2bf((xr[k] - mean[k]) / scale[k]);
    }
    fr[INL + g] = 0;
}

// ---- MFMA GEMM: out[m,n] = act(A(bf16) @ W(bf16 [N][K])^T + b1 + b2) ----
__global__ __launch_bounds__(256) void k_gemm(
    const u16* __restrict__ A, int lda,
    const u16* __restrict__ W, int K,
    const float* __restrict__ bias1, const float* __restrict__ bias2,
    void* __restrict__ out, int ldo, int kc_cnt, int do_relu, int out_half)
{
    __shared__ u16 sA[64*40];
    __shared__ u16 sB[256*40];
    int tid = threadIdx.x;
    int w = tid >> 6, lane = tid & 63, q = lane >> 4, r = lane & 15;
    int m0 = blockIdx.x * 64;
    int n0 = blockIdx.y * 256;

    f32x4 acc[4][4];
    for (int a_ = 0; a_ < 4; a_++)
        for (int b_ = 0; b_ < 4; b_++){
            acc[a_][b_][0] = 0.f; acc[a_][b_][1] = 0.f;
            acc[a_][b_][2] = 0.f; acc[a_][b_][3] = 0.f;
        }

    for (int kc = 0; kc < kc_cnt; kc++){
        {
            int row = tid >> 2, seg = tid & 3;
            uint4 v = *(const uint4*)(A + (size_t)(m0+row)*lda + kc*32 + seg*8);
            *(uint4*)(&sA[row*40 + seg*8]) = v;
            const u16* wr = W + (size_t)(n0 + tid)*K + kc*32;
            uint4 b0 = *(const uint4*)(wr);
            uint4 b1 = *(const uint4*)(wr+8);
            uint4 b2 = *(const uint4*)(wr+16);
            uint4 b3 = *(const uint4*)(wr+24);
            u16* d = &sB[tid*40];
            *(uint4*)(d)    = b0; *(uint4*)(d+8)  = b1;
            *(uint4*)(d+16) = b2; *(uint4*)(d+24) = b3;
        }
        __syncthreads();
        bf16x8 a[4], b[4];
        for (int mt = 0; mt < 4; mt++) a[mt] = *(const bf16x8*)(&sA[(mt*16 + r)*40 + q*8]);
        for (int i = 0; i < 4; i++)    b[i]  = *(const bf16x8*)(&sB[((w*4+i)*16 + r)*40 + q*8]);
        for (int mt = 0; mt < 4; mt++)
            for (int i = 0; i < 4; i++)
                acc[mt][i] = __builtin_amdgcn_mfma_f32_16x16x32_bf16(a[mt], b[i], acc[mt][i], 0, 0, 0);
        __syncthreads();
    }

    for (int i = 0; i < 4; i++){
        int n = n0 + (w*4+i)*16 + r;
        float bs = 0.f;
        if (bias1) bs += bias1[n];
        if (bias2) bs += bias2[n];
        for (int mt = 0; mt < 4; mt++){
            for (int reg = 0; reg < 4; reg++){
                int m = m0 + mt*16 + q*4 + reg;
                float v = acc[mt][i][reg] + bs;
                if (do_relu) v = fmaxf(v, 0.f);
                if (out_half) ((_Float16*)out)[(size_t)m*ldo + n] = (_Float16)v;
                else          ((u16*)out)[(size_t)m*ldo + n] = f2bf(v);
            }
        }
    }
}

// ---- zero barrier flags: 4 groups x 32 flags x 16 ints (64-B spaced) ----
__global__ void k_zcnt(int* bar){
    int i = blockIdx.x*256 + threadIdx.x;
    if (i < 4*GRPB*16) bar[i] = 0;
}

// ---- PERSISTENT recurrence v3: flag-array barrier + xw prefetch ----
// grid 128 = 4 m-groups x 32 j-blocks. Block: m0 = (bid&3)*64, j0 = (bid>>2)*16.
// Whh slice (64 n-rows x 512 k = 65536 B) LDS-resident, XOR-swizzled 16B chunks.
// Per-step sync: each block release-stores its OWN 64B-spaced flag (no same-line
// RMW serialization); wave0 polls all 32 flags in parallel (1 load/poll);
// single acquire-load invalidates L1/L2 before next step's h reads.
__global__ __launch_bounds__(256) void k_rec_seq(
    const u16* __restrict__ Whhb,       // bf16 [2048][512] layer slice
    const _Float16* __restrict__ xw,    // [MTOT][2048], biases folded
    u16* __restrict__ hA,
    u16* __restrict__ hB,
    u16* __restrict__ Xout,             // relu(h) sequence (layer 0) or null
    int* __restrict__ bar)
{
    __shared__ u16 sB[64*512];   // exactly 65536 B
    int tid = threadIdx.x;
    int w = tid >> 6, lane = tid & 63, q = lane >> 4, r = lane & 15;
    int mg = blockIdx.x & 3;
    int jb = blockIdx.x >> 2;
    int m0 = mg * 64;
    int j0 = jb * 16;
    int* flags = bar + mg * (GRPB*16);   // this group's flag array (32 x 64 B)
    int j = j0 + r;

    {   // stage B once: row n (g=n>>4, jj=n&15) <- Whhb[g*512 + j0 + jj][:]
        int row = tid >> 2, seg = tid & 3;   // 4 threads/row, 16 chunks (of 8 u16) each
        int g = row >> 4, jj = row & 15;
        const u16* src = Whhb + (size_t)(g*HH + j0 + jj)*HH;
        for (int i = 0; i < 16; i++){
            int c = seg*16 + i;
            *(uint4*)(&sB[row*512 + ((c ^ (row & 7)) * 8)]) = *(const uint4*)(src + c*8);
        }
    }
    // zero my hA cells; c lives in registers for the whole sequence
    float creg[4] = {0.f, 0.f, 0.f, 0.f};
    for (int reg = 0; reg < 4; reg++){
        int m = m0 + w*16 + q*4 + reg;
        hA[m*HH + j] = 0;
    }

    for (int t = -1; t < TT; t++){
        if (t >= 0){
            const u16* hp = (t & 1) ? hB : hA;
            u16*       hn = (t & 1) ? hA : hB;
            const u16* aRow = hp + (size_t)(m0 + w*16 + r)*HH;

            // prefetch xw gate-addends for this step (independent of h; hides
            // post-invalidate L3/HBM latency under the MFMA chain)
            float xadd[4][4];   // [reg][gate]
            for (int reg = 0; reg < 4; reg++){
                int m = m0 + w*16 + q*4 + reg;
                const _Float16* xr = xw + ((size_t)m*TT + t)*G4 + j;
                for (int g = 0; g < 4; g++)
                    xadd[reg][g] = (float)__builtin_nontemporal_load(xr + g*HH);
            }

            f32x4 acc[4];
            for (int g = 0; g < 4; g++){
                acc[g][0] = 0.f; acc[g][1] = 0.f; acc[g][2] = 0.f; acc[g][3] = 0.f;
            }
            for (int kc = 0; kc < 16; kc++){
                bf16x8 a = *(const bf16x8*)(aRow + kc*32 + q*8);
                int cbase = kc*4 + q;
                for (int g = 0; g < 4; g++){
                    int row = g*16 + r;
                    bf16x8 b = *(const bf16x8*)(&sB[row*512 + ((cbase ^ (row & 7)) * 8)]);
                    acc[g] = __builtin_amdgcn_mfma_f32_16x16x32_bf16(a, b, acc[g], 0, 0, 0);
                }
            }
            // cell update: all 4 gates of (m,j) in this lane; c in registers
            for (int reg = 0; reg < 4; reg++){
                int m = m0 + w*16 + q*4 + reg;
                float Gi = acc[0][reg] + xadd[reg][0];
                float Gf = acc[1][reg] + xadd[reg][1];
                float Gg = acc[2][reg] + xadd[reg][2];
                float Go = acc[3][reg] + xadd[reg][3];
                float iv = 1.f/(1.f + __expf(-Gi));
                float fv = 1.f/(1.f + __expf(-Gf));
                float gv = tanhf(Gg);
                float ov = 1.f/(1.f + __expf(-Go));
                float c = fv * creg[reg] + iv * gv;
                creg[reg] = c;
                float h = ov * tanhf(c);
                hn[m*HH + j] = f2bf(h);
                if (Xout){
                    size_t bt = (size_t)m*TT + t;
                    Xout[bt*HH + j] = f2bf(fmaxf(h, 0.f));
                }
            }
        }
        // flag-array m-group barrier
        __syncthreads();   // all threads' h stores issued & drained (vmcnt0 before barrier)
        if (tid == 0)
            __hip_atomic_store(&flags[jb*16], t + 2, __ATOMIC_RELEASE,
                               __HIP_MEMORY_SCOPE_AGENT);
        if (tid < 64){
            if (lane < GRPB){
                long long t0 = clock64();
                while (__hip_atomic_load(&flags[lane*16], __ATOMIC_RELAXED,
                                         __HIP_MEMORY_SCOPE_AGENT) < t + 2){
                    __builtin_amdgcn_s_sleep(1);
                    if (clock64() - t0 > 50000000LL) break;   // watchdog: degrade, not hang
                }
            }
            if (lane == 0)
                (void)__hip_atomic_load(&flags[0], __ATOMIC_ACQUIRE,
                                        __HIP_MEMORY_SCOPE_AGENT);
        }
        __syncthreads();
    }
}

// ---- heads: fp32 output (d_out is float*), zero-sentinel kept ----
__global__ void k_heads(
    const u16* __restrict__ hfin, const float* __restrict__ Wout,
    const float* __restrict__ bout, const float* __restrict__ Wcls,
    const float* __restrict__ bcls, float* __restrict__ out)
{
    __shared__ float last[HH];
    int b = blockIdx.x, tid = threadIdx.x;
    for (int h = tid; h < HH; h += 256) last[h] = fmaxf(bf2f(hfin[b*HH + h]), 0.f);
    __syncthreads();
    for (int o = tid; o < NCONT + NCAT*VV; o += 256){
        if (o < NCONT){
            float a = bout[o];
            for (int h = 0; h < HH; h++) a += last[h] * Wout[h*NCONT + o];
            out[b*NCONT + o] = (a == 0.0f) ? 7.0f : a;
        } else {
            int oc = o - NCONT;
            int n = oc >> 5, v = oc & 31;
            float a = bcls[oc];
            const float* wp = Wcls + (size_t)n*HH*VV + v;
            for (int h = 0; h < HH; h++) a += last[h] * wp[h*VV];
            out[BB*NCONT + b*(NCAT*VV) + oc] = (a == 0.0f) ? 7.0f : a;
        }
    }
}

extern "C" void kernel_launch(void* const* d_in, const int* in_sizes, int n_in,
                              void* d_out, int out_size, void* d_ws, size_t ws_size,
                              hipStream_t stream){
    const float* x      = (const float*)d_in[0];
    const float* smean  = (const float*)d_in[1];
    const float* sscale = (const float*)d_in[2];
    const float* emb    = (const float*)d_in[3];
    const float* Win    = (const float*)d_in[4];
    const float* bin    = (const float*)d_in[5];
    const float* Wih    = (const float*)d_in[6];
    const float* Whh    = (const float*)d_in[7];
    const float* bih    = (const float*)d_in[8];
    const float* bhh    = (const float*)d_in[9];
    const float* Wout   = (const float*)d_in[10];
    const float* bout   = (const float*)d_in[11];
    const float* Wcls   = (const float*)d_in[12];
    const float* bcls   = (const float*)d_in[13];
    (void)in_sizes; (void)n_in; (void)out_size;

    char* ws = (char*)d_ws;
    size_t off = 0;
    u16*      feat  = (u16*)(ws + off);      off += (size_t)MTOT*KIN*2;   //   9.8 MB
    u16*      WinTb = (u16*)(ws + off);      off += (size_t)HH*KIN*2;     //   0.2 MB
    u16*      Xbuf  = (u16*)(ws + off);      off += (size_t)MTOT*HH*2;    //  26.2 MB
    _Float16* xw    = (_Float16*)(ws + off); off += (size_t)MTOT*G4*2;    // 104.9 MB
    u16*      Wihb  = (u16*)(ws + off);      off += (size_t)2*G4*HH*2;    //   4.2 MB
    u16*      Whhb  = (u16*)(ws + off);      off += (size_t)2*G4*HH*2;    //   4.2 MB
    u16*      hA    = (u16*)(ws + off);      off += (size_t)BB*HH*2;
    u16*      hB    = (u16*)(ws + off);      off += (size_t)BB*HH*2;
    int*      bar   = (int*)(ws + off);      off += 4*GRPB*16*4;          //   8 KB
    (void)off; (void)ws_size;

    // weight prep (bf16 once)
    PredictionModel_58841051955204_kernel<<<384, 256, 0, stream>>>(Win, WinTb);
    k_cvt<<<8192, 256, 0, stream>>>(Wih, Wihb, 2*G4*HH);
    k_cvt<<<8192, 256, 0, stream>>>(Whh, Whhb, 2*G4*HH);

    k_feat<<<1600, 256, 0, stream>>>(x, smean, sscale, emb, feat);
    // h0 = relu(feat @ W_in + b_in) -> Xbuf (bf16)
    k_gemm<<<dim3(400, 2), 256, 0, stream>>>(feat, KIN, WinTb, KIN, bin, (const float*)0,
                                             Xbuf, HH, 6, 1, 0);
    for (int l = 0; l < 2; l++){
        // xw = Xbuf @ Wih_l^T + bih_l + bhh_l -> fp16 (Xbuf consumed before rec overwrites it)
        k_gemm<<<dim3(400, 8), 256, 0, stream>>>(Xbuf, HH, Wihb + (size_t)l*G4*HH, HH,
                                                 bih + l*G4, bhh + l*G4,
                                                 xw, G4, 16, 0, 1);
        k_zcnt<<<8, 256, 0, stream>>>(bar);
        k_rec_seq<<<128, 256, 0, stream>>>(Whhb + (size_t)l*G4*HH, xw, hA, hB,
                                           (l == 0) ? Xbuf : (u16*)0, bar);
    }
    // T=100 even -> final h in hA; heads write fp32 d_out
    k_heads<<<256, 256, 0, stream>>>(hA, Wout, bout, Wcls, bcls, (float*)d_out);
}

// Round 23
// 1967.327 us; speedup vs baseline: 6.1384x; 1.2046x over previous
//
#include <hip/hip_runtime.h>

#define BB 256
#define TT 100
#define HH 512
#define G4 2048
#define INL 176
#define KIN 192
#define NCAT 16
#define NCONT 48
#define VV 32
#define EE 8
#define MTOT (BB*TT)
#define GRPB 32   // j-blocks per m-group

typedef unsigned short u16;
typedef unsigned int   u32;
typedef unsigned long long u64;
typedef __attribute__((ext_vector_type(8))) short bf16x8;
typedef __attribute__((ext_vector_type(4))) float f32x4;

__device__ __forceinline__ float bf2f(u16 u){
    union { u32 i; float f; } v; v.i = ((u32)u) << 16; return v.f;
}
__device__ __forceinline__ u16 f2bf(float f){
    union { float f; u32 i; } v; v.f = f;
    u32 b = v.i;
    b += 0x7FFFu + ((b >> 16) & 1u);   // round-to-nearest-even
    return (u16)(b >> 16);
}

// ---- canonical-name kernel: W_in fp32 [176][512] -> bf16 WinT [512][192] (pad) ----
__global__ void PredictionModel_58841051955204_kernel(
    const float* __restrict__ Win, u16* __restrict__ WinT){
    int idx = blockIdx.x*256 + threadIdx.x;
    if (idx >= HH*KIN) return;
    int h = idx / KIN, i = idx % KIN;
    WinT[idx] = (i < INL) ? f2bf(Win[i*HH + h]) : (u16)0;
}

// ---- bulk fp32 -> bf16 convert (weights) ----
__global__ void k_cvt(const float* __restrict__ in, u16* __restrict__ out, int n){
    int i = blockIdx.x*256 + threadIdx.x;
    if (i < n) out[i] = f2bf(in[i]);
}

// ---- featurize: fp32 inputs -> bf16 feat [25600][192] ----
__global__ void k_feat(const float* __restrict__ x, const float* __restrict__ mean,
                       const float* __restrict__ scale, const float* __restrict__ emb,
                       u16* __restrict__ feat){
    int idx = blockIdx.x*256 + threadIdx.x;
    int bt = idx >> 4, g = idx & 15;
    if (bt >= MTOT) return;
    const float* xr = x + (size_t)bt*64;
    u16* fr = feat + (size_t)bt*KIN;
    int k0 = g*4;
    int ci = (int)xr[k0];
    if (ci < 0) ci = 0;
    if (ci > VV-1) ci = VV-1;
    const float* ep = emb + (size_t)(g*VV + ci)*EE;
    int c0 = g*11;
    for (int e = 0; e < 8; e++) fr[c0+e] = f2bf(ep[e]);
    for (int j = 1; j <= 3; j++){
        int k = k0 + j;
        fr[c0 + 8 + (j-1)] = f2bf((xr[k] - mean[k]) / scale[k]);
    }
    fr[INL + g] = 0;
}

// ---- MFMA GEMM: out[m,n] = act(A(bf16) @ W(bf16 [N][K])^T + b1 + b2) ----
__global__ __launch_bounds__(256) void k_gemm(
    const u16* __restrict__ A, int lda,
    const u16* __restrict__ W, int K,
    const float* __restrict__ bias1, const float* __restrict__ bias2,
    void* __restrict__ out, int ldo, int kc_cnt, int do_relu, int out_half)
{
    __shared__ u16 sA[64*40];
    __shared__ u16 sB[256*40];
    int tid = threadIdx.x;
    int w = tid >> 6, lane = tid & 63, q = lane >> 4, r = lane & 15;
    int m0 = blockIdx.x * 64;
    int n0 = blockIdx.y * 256;

    f32x4 acc[4][4];
    for (int a_ = 0; a_ < 4; a_++)
        for (int b_ = 0; b_ < 4; b_++){
            acc[a_][b_][0] = 0.f; acc[a_][b_][1] = 0.f;
            acc[a_][b_][2] = 0.f; acc[a_][b_][3] = 0.f;
        }

    for (int kc = 0; kc < kc_cnt; kc++){
        {
            int row = tid >> 2, seg = tid & 3;
            uint4 v = *(const uint4*)(A + (size_t)(m0+row)*lda + kc*32 + seg*8);
            *(uint4*)(&sA[row*40 + seg*8]) = v;
            const u16* wr = W + (size_t)(n0 + tid)*K + kc*32;
            uint4 b0 = *(const uint4*)(wr);
            uint4 b1 = *(const uint4*)(wr+8);
            uint4 b2 = *(const uint4*)(wr+16);
            uint4 b3 = *(const uint4*)(wr+24);
            u16* d = &sB[tid*40];
            *(uint4*)(d)    = b0; *(uint4*)(d+8)  = b1;
            *(uint4*)(d+16) = b2; *(uint4*)(d+24) = b3;
        }
        __syncthreads();
        bf16x8 a[4], b[4];
        for (int mt = 0; mt < 4; mt++) a[mt] = *(const bf16x8*)(&sA[(mt*16 + r)*40 + q*8]);
        for (int i = 0; i < 4; i++)    b[i]  = *(const bf16x8*)(&sB[((w*4+i)*16 + r)*40 + q*8]);
        for (int mt = 0; mt < 4; mt++)
            for (int i = 0; i < 4; i++)
                acc[mt][i] = __builtin_amdgcn_mfma_f32_16x16x32_bf16(a[mt], b[i], acc[mt][i], 0, 0, 0);
        __syncthreads();
    }

    for (int i = 0; i < 4; i++){
        int n = n0 + (w*4+i)*16 + r;
        float bs = 0.f;
        if (bias1) bs += bias1[n];
        if (bias2) bs += bias2[n];
        for (int mt = 0; mt < 4; mt++){
            for (int reg = 0; reg < 4; reg++){
                int m = m0 + mt*16 + q*4 + reg;
                float v = acc[mt][i][reg] + bs;
                if (do_relu) v = fmaxf(v, 0.f);
                if (out_half) ((_Float16*)out)[(size_t)m*ldo + n] = (_Float16)v;
                else          ((u16*)out)[(size_t)m*ldo + n] = f2bf(v);
            }
        }
    }
}

// ---- zero barrier flags ----
__global__ void k_zcnt(int* bar){
    int i = blockIdx.x*256 + threadIdx.x;
    if (i < 4*GRPB*16) bar[i] = 0;
}

// ---- PERSISTENT recurrence v4: SC1-coherent h exchange, NO cache maintenance ----
// grid 128 = 4 m-groups x 32 j-blocks. Block: m0 = (bid&3)*64, j0 = (bid>>2)*16.
// Whh slice LDS-resident (XOR-swizzled). h exchanged as u64 relaxed AGENT atomics:
// SC1 accesses bypass the non-coherent L2 (hit the device coherence point), so no
// wbL2/invL2 per step. Flags are relaxed too; __syncthreads' vmcnt(0) drain means a
// retired SC1 store is globally visible before the flag store issues.
__global__ __launch_bounds__(256) void k_rec_seq(
    const u16* __restrict__ Whhb,       // bf16 [2048][512] layer slice
    const _Float16* __restrict__ xw,    // [MTOT][2048], biases folded
    u64* __restrict__ h64A,             // [256][128] u64 (= bf16 [256][512])
    u64* __restrict__ h64B,
    u16* __restrict__ Xout,             // relu(h) sequence (layer 0) or null
    int* __restrict__ bar)
{
    __shared__ u16 sB[64*512];   // exactly 65536 B
    int tid = threadIdx.x;
    int w = tid >> 6, lane = tid & 63, q = lane >> 4, r = lane & 15;
    int mg = blockIdx.x & 3;
    int jb = blockIdx.x >> 2;
    int m0 = mg * 64;
    int j0 = jb * 16;
    int* flags = bar + mg * (GRPB*16);
    int j = j0 + r;

    {   // stage B once: row n (g=n>>4, jj=n&15) <- Whhb[g*512 + j0 + jj][:]
        int row = tid >> 2, seg = tid & 3;
        int g = row >> 4, jj = row & 15;
        const u16* src = Whhb + (size_t)(g*HH + j0 + jj)*HH;
        for (int i = 0; i < 16; i++){
            int c = seg*16 + i;
            *(uint4*)(&sB[row*512 + ((c ^ (row & 7)) * 8)]) = *(const uint4*)(src + c*8);
        }
    }
    // zero my hA cells (SC1 stores so they're coherently visible after barrier 0)
    float creg[4] = {0.f, 0.f, 0.f, 0.f};
    if ((r & 3) == 0){
        for (int reg = 0; reg < 4; reg++){
            int m = m0 + w*16 + q*4 + reg;
            __hip_atomic_store(&h64A[(size_t)m*(HH/4) + ((j0 + r) >> 2)], 0ULL,
                               __ATOMIC_RELAXED, __HIP_MEMORY_SCOPE_AGENT);
        }
    }

    for (int t = -1; t < TT; t++){
        if (t >= 0){
            const u64* hsrc = (t & 1) ? h64B : h64A;
            u64*       hdst = (t & 1) ? h64A : h64B;
            const u64* hrow = hsrc + (size_t)(m0 + w*16 + r)*(HH/4);

            // prefetch xw gate-addends (independent of h)
            float xadd[4][4];
            for (int reg = 0; reg < 4; reg++){
                int m = m0 + w*16 + q*4 + reg;
                const _Float16* xr = xw + ((size_t)m*TT + t)*G4 + j;
                for (int g = 0; g < 4; g++)
                    xadd[reg][g] = (float)__builtin_nontemporal_load(xr + g*HH);
            }

            f32x4 acc[4];
            for (int g = 0; g < 4; g++){
                acc[g][0] = 0.f; acc[g][1] = 0.f; acc[g][2] = 0.f; acc[g][3] = 0.f;
            }
            for (int kc = 0; kc < 16; kc++){
                union { u64 d[2]; bf16x8 v; } au;
                int jg0 = kc*8 + q*2;
                au.d[0] = __hip_atomic_load(&hrow[jg0],   __ATOMIC_RELAXED, __HIP_MEMORY_SCOPE_AGENT);
                au.d[1] = __hip_atomic_load(&hrow[jg0+1], __ATOMIC_RELAXED, __HIP_MEMORY_SCOPE_AGENT);
                int cbase = kc*4 + q;
                for (int g = 0; g < 4; g++){
                    int row = g*16 + r;
                    bf16x8 b = *(const bf16x8*)(&sB[row*512 + ((cbase ^ (row & 7)) * 8)]);
                    acc[g] = __builtin_amdgcn_mfma_f32_16x16x32_bf16(au.v, b, acc[g], 0, 0, 0);
                }
            }

            // cell update + SC1 h store (u64-packed via cross-lane shuffles)
            for (int reg = 0; reg < 4; reg++){
                int m = m0 + w*16 + q*4 + reg;
                float Gi = acc[0][reg] + xadd[reg][0];
                float Gf = acc[1][reg] + xadd[reg][1];
                float Gg = acc[2][reg] + xadd[reg][2];
                float Go = acc[3][reg] + xadd[reg][3];
                float iv = 1.f/(1.f + __expf(-Gi));
                float fv = 1.f/(1.f + __expf(-Gf));
                float gv = tanhf(Gg);
                float ov = 1.f/(1.f + __expf(-Go));
                float c = fv * creg[reg] + iv * gv;
                creg[reg] = c;
                float h = ov * tanhf(c);
                u32 own = (u32)f2bf(h);
                u32 p01 = own | (((u32)__shfl_xor((int)own, 1)) << 16);  // (j, j+1) on even r
                u32 p23 = (u32)__shfl_xor((int)p01, 2);                  // (j+2, j+3) from r+2
                if ((r & 3) == 0){
                    u64 pk = (u64)p01 | ((u64)p23 << 32);
                    __hip_atomic_store(&hdst[(size_t)m*(HH/4) + ((j0 + r) >> 2)], pk,
                                       __ATOMIC_RELAXED, __HIP_MEMORY_SCOPE_AGENT);
                }
                if (Xout){
                    size_t bt = (size_t)m*TT + t;
                    __builtin_nontemporal_store(f2bf(fmaxf(h, 0.f)), Xout + bt*HH + j);
                }
            }
        }
        // flag-array m-group barrier, all relaxed SC1 (no wb/inv):
        __syncthreads();   // drains vmcnt(0): every SC1 h-store retired => globally visible
        if (tid == 0)
            __hip_atomic_store(&flags[jb*16], t + 2, __ATOMIC_RELAXED,
                               __HIP_MEMORY_SCOPE_AGENT);
        if (tid < 64 && lane < GRPB){
            long long t0 = clock64();
            while (__hip_atomic_load(&flags[lane*16], __ATOMIC_RELAXED,
                                     __HIP_MEMORY_SCOPE_AGENT) < t + 2){
                __builtin_amdgcn_s_sleep(1);
                if (clock64() - t0 > 50000000LL) break;   // watchdog: degrade, not hang
            }
        }
        __syncthreads();
    }
}

// ---- heads: fp32 output (d_out is float*), zero-sentinel kept ----
__global__ void k_heads(
    const u16* __restrict__ hfin, const float* __restrict__ Wout,
    const float* __restrict__ bout, const float* __restrict__ Wcls,
    const float* __restrict__ bcls, float* __restrict__ out)
{
    __shared__ float last[HH];
    int b = blockIdx.x, tid = threadIdx.x;
    for (int h = tid; h < HH; h += 256) last[h] = fmaxf(bf2f(hfin[b*HH + h]), 0.f);
    __syncthreads();
    for (int o = tid; o < NCONT + NCAT*VV; o += 256){
        if (o < NCONT){
            float a = bout[o];
            for (int h = 0; h < HH; h++) a += last[h] * Wout[h*NCONT + o];
            out[b*NCONT + o] = (a == 0.0f) ? 7.0f : a;
        } else {
            int oc = o - NCONT;
            int n = oc >> 5, v = oc & 31;
            float a = bcls[oc];
            const float* wp = Wcls + (size_t)n*HH*VV + v;
            for (int h = 0; h < HH; h++) a += last[h] * wp[h*VV];
            out[BB*NCONT + b*(NCAT*VV) + oc] = (a == 0.0f) ? 7.0f : a;
        }
    }
}

extern "C" void kernel_launch(void* const* d_in, const int* in_sizes, int n_in,
                              void* d_out, int out_size, void* d_ws, size_t ws_size,
                              hipStream_t stream){
    const float* x      = (const float*)d_in[0];
    const float* smean  = (const float*)d_in[1];
    const float* sscale = (const float*)d_in[2];
    const float* emb    = (const float*)d_in[3];
    const float* Win    = (const float*)d_in[4];
    const float* bin    = (const float*)d_in[5];
    const float* Wih    = (const float*)d_in[6];
    const float* Whh    = (const float*)d_in[7];
    const float* bih    = (const float*)d_in[8];
    const float* bhh    = (const float*)d_in[9];
    const float* Wout   = (const float*)d_in[10];
    const float* bout   = (const float*)d_in[11];
    const float* Wcls   = (const float*)d_in[12];
    const float* bcls   = (const float*)d_in[13];
    (void)in_sizes; (void)n_in; (void)out_size;

    char* ws = (char*)d_ws;
    size_t off = 0;
    u16*      feat  = (u16*)(ws + off);      off += (size_t)MTOT*KIN*2;   //   9.8 MB
    u16*      WinTb = (u16*)(ws + off);      off += (size_t)HH*KIN*2;     //   0.2 MB
    u16*      Xbuf  = (u16*)(ws + off);      off += (size_t)MTOT*HH*2;    //  26.2 MB
    _Float16* xw    = (_Float16*)(ws + off); off += (size_t)MTOT*G4*2;    // 104.9 MB
    u16*      Wihb  = (u16*)(ws + off);      off += (size_t)2*G4*HH*2;    //   4.2 MB
    u16*      Whhb  = (u16*)(ws + off);      off += (size_t)2*G4*HH*2;    //   4.2 MB
    u64*      hA    = (u64*)(ws + off);      off += (size_t)BB*HH*2;
    u64*      hB    = (u64*)(ws + off);      off += (size_t)BB*HH*2;
    int*      bar   = (int*)(ws + off);      off += 4*GRPB*16*4;          //   8 KB
    (void)off; (void)ws_size;

    // weight prep (bf16 once)
    PredictionModel_58841051955204_kernel<<<384, 256, 0, stream>>>(Win, WinTb);
    k_cvt<<<8192, 256, 0, stream>>>(Wih, Wihb, 2*G4*HH);
    k_cvt<<<8192, 256, 0, stream>>>(Whh, Whhb, 2*G4*HH);

    k_feat<<<1600, 256, 0, stream>>>(x, smean, sscale, emb, feat);
    // h0 = relu(feat @ W_in + b_in) -> Xbuf (bf16)
    k_gemm<<<dim3(400, 2), 256, 0, stream>>>(feat, KIN, WinTb, KIN, bin, (const float*)0,
                                             Xbuf, HH, 6, 1, 0);
    for (int l = 0; l < 2; l++){
        // xw = Xbuf @ Wih_l^T + bih_l + bhh_l -> fp16 (Xbuf consumed before rec overwrites it)
        k_gemm<<<dim3(400, 8), 256, 0, stream>>>(Xbuf, HH, Wihb + (size_t)l*G4*HH, HH,
                                                 bih + l*G4, bhh + l*G4,
                                                 xw, G4, 16, 0, 1);
        k_zcnt<<<8, 256, 0, stream>>>(bar);
        k_rec_seq<<<128, 256, 0, stream>>>(Whhb + (size_t)l*G4*HH, xw, hA, hB,
                                           (l == 0) ? Xbuf : (u16*)0, bar);
    }
    // T=100 even -> final h in hA; heads write fp32 d_out
    k_heads<<<256, 256, 0, stream>>>((const u16*)hA, Wout, bout, Wcls, bcls, (float*)d_out);
}